// Round 1
// baseline (154.252 us; speedup 1.0000x reference)
//
#include <hip/hip_runtime.h>

// ---------------- problem constants ----------------
#define B_     16
#define L_     1024
#define D_     768
#define C_     500
#define J_     10
#define M_     (B_ * L_)        // 16384
#define NREAL  (C_ * J_)        // 5000
#define NPAD   5120             // 40 * 128
#define TM     128
#define TN     128
#define TK     64
#define KITERS (D_ / TK)        // 12

typedef __attribute__((ext_vector_type(8))) short short8;
typedef __attribute__((ext_vector_type(4))) float f32x4;

// float <-> order-preserving uint (for atomicMax on signed floats)
static __device__ __forceinline__ unsigned f2ord(float f) {
    unsigned u = __float_as_uint(f);
    return (u & 0x80000000u) ? ~u : (u | 0x80000000u);
}
static __device__ __forceinline__ float ord2f(unsigned u) {
    return (u & 0x80000000u) ? __uint_as_float(u & 0x7fffffffu)
                             : __uint_as_float(~u);
}

// fp32 -> bf16 round-to-nearest-even
static __device__ __forceinline__ unsigned short f2bf(float f) {
    unsigned u = __float_as_uint(f);
    u += 0x7fffu + ((u >> 16) & 1u);
    return (unsigned short)(u >> 16);
}

// ---------------- kernel 1/2: L2-normalize rows fp32 -> bf16 ----------------
// one wave per row; 768 = 64 lanes * 3 float4
__global__ __launch_bounds__(256) void norm_rows_kernel(
    const float* __restrict__ in, unsigned short* __restrict__ out,
    int nrows, int valid_rows)
{
    int row  = blockIdx.x * 4 + (threadIdx.x >> 6);
    int lane = threadIdx.x & 63;
    if (row >= nrows) return;

    unsigned short* orow = out + (size_t)row * D_;
    if (row >= valid_rows) {               // zero pad rows
        ushort4 z = {0, 0, 0, 0};
        #pragma unroll
        for (int p = 0; p < 3; ++p)
            *(ushort4*)(orow + (p * 64 + lane) * 4) = z;
        return;
    }

    const float4* rp = (const float4*)(in + (size_t)row * D_);
    float4 v[3];
    float s = 0.f;
    #pragma unroll
    for (int p = 0; p < 3; ++p) {
        v[p] = rp[p * 64 + lane];
        s += v[p].x * v[p].x + v[p].y * v[p].y + v[p].z * v[p].z + v[p].w * v[p].w;
    }
    #pragma unroll
    for (int off = 32; off; off >>= 1) s += __shfl_xor(s, off);
    float inv = 1.f / fmaxf(sqrtf(s), 1e-12f);
    #pragma unroll
    for (int p = 0; p < 3; ++p) {
        ushort4 o;
        o.x = f2bf(v[p].x * inv);
        o.y = f2bf(v[p].y * inv);
        o.z = f2bf(v[p].z * inv);
        o.w = f2bf(v[p].w * inv);
        *(ushort4*)(orow + (p * 64 + lane) * 4) = o;
    }
}

// ---------------- kernel 3: GEMM (Z * P^T) with fused max-over-L ----------------
// m97 structure: 128x128 tile, BK=64, 4 waves (2x2), global_load_lds(16B), linear LDS.
__global__ __launch_bounds__(256, 2) void gemm_maxpool_kernel(
    const unsigned short* __restrict__ Z,   // [M_][D_] bf16 bits
    const unsigned short* __restrict__ P,   // [NPAD][D_] bf16 bits
    unsigned int* __restrict__ pooled)      // [B_][NPAD] ord-encoded max
{
    __shared__ unsigned short As[TM * TK];  // 16 KB
    __shared__ unsigned short Bs[TN * TK];  // 16 KB

    const int tid  = threadIdx.x;
    const int lane = tid & 63;
    const int wid  = tid >> 6;
    const int wm   = wid >> 1;
    const int wn   = wid & 1;

    const int bm = blockIdx.x & 127;        // 128 M-tiles
    const int bn = blockIdx.x >> 7;         // 40 N-tiles
    const int row0 = bm * TM;
    const int col0 = bn * TN;

    f32x4 acc[4][4] = {};

    const int lrow = lane & 15;
    const int lk8  = (lane >> 4) * 8;

    for (int kt = 0; kt < KITERS; ++kt) {
        const int k0 = kt * TK;
        #pragma unroll
        for (int i = 0; i < 4; ++i) {
            int e = (i * 256 + tid) * 8;    // element index in tile
            int r = e >> 6;                 // / TK
            int c = e & 63;                 // % TK
            const unsigned short* ga = Z + (size_t)(row0 + r) * D_ + k0 + c;
            __builtin_amdgcn_global_load_lds(
                (const __attribute__((address_space(1))) void*)ga,
                (__attribute__((address_space(3))) void*)(As + e), 16, 0, 0);
            const unsigned short* gb = P + (size_t)(col0 + r) * D_ + k0 + c;
            __builtin_amdgcn_global_load_lds(
                (const __attribute__((address_space(1))) void*)gb,
                (__attribute__((address_space(3))) void*)(Bs + e), 16, 0, 0);
        }
        __syncthreads();

        #pragma unroll
        for (int kk = 0; kk < 2; ++kk) {
            short8 a[4], b[4];
            #pragma unroll
            for (int mi = 0; mi < 4; ++mi)
                a[mi] = *(const short8*)(As + (wm * 64 + mi * 16 + lrow) * TK + kk * 32 + lk8);
            #pragma unroll
            for (int ni = 0; ni < 4; ++ni)
                b[ni] = *(const short8*)(Bs + (wn * 64 + ni * 16 + lrow) * TK + kk * 32 + lk8);
            #pragma unroll
            for (int mi = 0; mi < 4; ++mi)
                #pragma unroll
                for (int ni = 0; ni < 4; ++ni)
                    acc[mi][ni] = __builtin_amdgcn_mfma_f32_16x16x32_bf16(
                        a[mi], b[ni], acc[mi][ni], 0, 0, 0);
        }
        __syncthreads();
    }

    // epilogue: per-column max over this wave's 64 rows, then atomicMax.
    // C/D layout: col = lane&15, row = (lane>>4)*4 + reg
    const int batch = row0 >> 10;           // 1024 rows per batch; 128 | 1024
    #pragma unroll
    for (int ni = 0; ni < 4; ++ni) {
        float v = -3.0e38f;
        #pragma unroll
        for (int mi = 0; mi < 4; ++mi)
            v = fmaxf(v, fmaxf(fmaxf(acc[mi][ni][0], acc[mi][ni][1]),
                               fmaxf(acc[mi][ni][2], acc[mi][ni][3])));
        v = fmaxf(v, __shfl_xor(v, 16));
        v = fmaxf(v, __shfl_xor(v, 32));
        if (lane < 16) {
            int col = col0 + wn * 64 + ni * 16 + lane;
            atomicMax(&pooled[(size_t)batch * NPAD + col], f2ord(v));
        }
    }
}

// ---------------- kernel 4: finalize logits ----------------
__global__ __launch_bounds__(256) void finalize_kernel(
    const unsigned int* __restrict__ pooled,  // [B_][NPAD]
    const float* __restrict__ rw,             // [C_][J_]
    const float* __restrict__ bias,           // [C_]
    float* __restrict__ out)                  // [B_][C_]
{
    int t = blockIdx.x * 256 + threadIdx.x;
    if (t >= B_ * C_) return;
    int b = t / C_, c = t % C_;
    float s = 0.f;
    #pragma unroll
    for (int j = 0; j < J_; ++j) {
        float pv = ord2f(pooled[(size_t)b * NPAD + c * J_ + j]);
        float x  = rw[c * J_ + j];
        float w  = fmaxf(x, 0.f) + log1pf(expf(-fabsf(x)));  // softplus
        s += pv * w;
    }
    out[t] = s + bias[c];
}

// ---------------- launch ----------------
extern "C" void kernel_launch(void* const* d_in, const int* in_sizes, int n_in,
                              void* d_out, int out_size, void* d_ws, size_t ws_size,
                              hipStream_t stream) {
    const float* spatial = (const float*)d_in[0];   // (16,1024,768)
    const float* protos  = (const float*)d_in[1];   // (500,10,768)
    const float* rw      = (const float*)d_in[2];   // (500,10)
    const float* bias    = (const float*)d_in[3];   // (500,)
    float* out = (float*)d_out;                     // (16,500)

    unsigned short* z = (unsigned short*)d_ws;                    // 16384*768 bf16
    unsigned short* p = z + (size_t)M_ * D_;                      // 5120*768 bf16
    unsigned int* pooled = (unsigned int*)(p + (size_t)NPAD * D_); // 16*5120 u32

    // 1) normalize spatial -> bf16
    norm_rows_kernel<<<M_ / 4, 256, 0, stream>>>(spatial, z, M_, M_);
    // 2) normalize prototypes -> bf16 (padded rows zeroed)
    norm_rows_kernel<<<NPAD / 4, 256, 0, stream>>>(protos, p, NPAD, NREAL);
    // 3) clear pooled, then GEMM + fused max-pool
    hipMemsetAsync(pooled, 0, (size_t)B_ * NPAD * sizeof(unsigned int), stream);
    gemm_maxpool_kernel<<<(M_ / TM) * (NPAD / TN), 256, 0, stream>>>(z, p, pooled);
    // 4) finalize
    finalize_kernel<<<(B_ * C_ + 255) / 256, 256, 0, stream>>>(pooled, rw, bias, out);
}